// Round 1
// baseline (337.066 us; speedup 1.0000x reference)
//
#include <hip/hip_runtime.h>
#include <cstdint>
#include <cstddef>

#define H 1024
#define V 50257
#define B 64
#define T 512

__device__ __forceinline__ float sigmoidf_(float x) { return 1.0f / (1.0f + expf(-x)); }

// ---------------------------------------------------------------------------
// Embedding gather: X[b][h] = emb[seq[b]][h]
__global__ void k_embed(const int* __restrict__ seq, const float* __restrict__ emb,
                        float* __restrict__ X) {
    int i = blockIdx.x * 256 + threadIdx.x;   // 65536 total
    int b = i >> 10, h = i & 1023;
    X[i] = emb[(size_t)seq[b] * H + h];
}

// ---------------------------------------------------------------------------
// Generic split-K tiled GEMM, M fixed = 64 (all batch rows), BN = 64, BK = 32.
// BT=true : C[m,n] = sum_k A[m,k] * Bm[n,k]   (Bm is [N,K] row-major, ldb=K)
// BT=false: C[m,n] = sum_k A[m,k] * Bm[k,n]   (Bm is [K,N] row-major, ldb=N)
// Writes partial sums: Cp[blockIdx.y][m][n]  (caller sums over grid.y chunks)
template <bool BT>
__global__ __launch_bounds__(256) void gemm64(const float* __restrict__ A, int lda,
                                              const float* __restrict__ Bm, int ldb,
                                              float* __restrict__ Cp, int N, int KC) {
    __shared__ __align__(16) float As[32][68];
    __shared__ __align__(16) float Bs[32][68];
    const int t = threadIdx.x;
    const int n0 = blockIdx.x * 64;
    const int k0 = blockIdx.y * KC;
    const int tm = t >> 4, tn = t & 15;
    float acc[4][4] = {};
    for (int kk = k0; kk < k0 + KC; kk += 32) {
#pragma unroll
        for (int i = 0; i < 8; ++i) {
            int idx = t + i * 256;
            int m = idx >> 5, k = idx & 31;
            As[k][m] = A[(size_t)m * lda + kk + k];
        }
        if (BT) {
#pragma unroll
            for (int i = 0; i < 8; ++i) {
                int idx = t + i * 256;
                int n = idx >> 5, k = idx & 31;
                Bs[k][n] = Bm[(size_t)(n0 + n) * ldb + kk + k];
            }
        } else {
#pragma unroll
            for (int i = 0; i < 8; ++i) {
                int k = (t >> 6) + i * 4, n = t & 63;
                Bs[k][n] = Bm[(size_t)(kk + k) * ldb + n0 + n];
            }
        }
        __syncthreads();
#pragma unroll
        for (int k = 0; k < 32; ++k) {
            float4 a = *(const float4*)&As[k][tm * 4];
            float4 b = *(const float4*)&Bs[k][tn * 4];
            float av[4] = {a.x, a.y, a.z, a.w};
            float bv[4] = {b.x, b.y, b.z, b.w};
#pragma unroll
            for (int i = 0; i < 4; ++i)
#pragma unroll
                for (int j = 0; j < 4; ++j) acc[i][j] += av[i] * bv[j];
        }
        __syncthreads();
    }
    float* C = Cp + (size_t)blockIdx.y * 64 * N;
#pragma unroll
    for (int i = 0; i < 4; ++i)
#pragma unroll
        for (int j = 0; j < 4; ++j)
            C[(size_t)(tm * 4 + i) * N + n0 + tn * 4 + j] = acc[i][j];
}

// ---------------------------------------------------------------------------
// GRU gate combine: r,z,n gates -> h. Writes h into cat[:, :H] and hidden out.
__global__ void k_gru(const float* __restrict__ Pgi, const float* __restrict__ Pgh,
                      const float* __restrict__ bih, const float* __restrict__ bhh,
                      const float* __restrict__ h0, float* __restrict__ cat,
                      float* __restrict__ hid) {
    int i = blockIdx.x * 256 + threadIdx.x;   // 65536
    int b = i >> 10, h = i & 1023;
    float gr = bih[h], gz = bih[H + h], gn = bih[2 * H + h];
    float hr = bhh[h], hz = bhh[H + h], hn = bhh[2 * H + h];
#pragma unroll
    for (int kt = 0; kt < 4; ++kt) {
        const float* pi = Pgi + (size_t)kt * B * 3 * H + (size_t)b * 3 * H;
        const float* ph = Pgh + (size_t)kt * B * 3 * H + (size_t)b * 3 * H;
        gr += pi[h]; gz += pi[H + h]; gn += pi[2 * H + h];
        hr += ph[h]; hz += ph[H + h]; hn += ph[2 * H + h];
    }
    float r = sigmoidf_(gr + hr);
    float z = sigmoidf_(gz + hz);
    float n = tanhf(gn + r * hn);
    float hv = (1.0f - z) * n + z * h0[i];
    cat[(size_t)b * 2 * H + h] = hv;
    hid[i] = hv;
}

// u = sum over split-K partials
__global__ void k_sumu(const float* __restrict__ Pu, float* __restrict__ u) {
    int i = blockIdx.x * 256 + threadIdx.x;
    float s = 0.f;
#pragma unroll
    for (int kt = 0; kt < 4; ++kt) s += Pu[kt * (B * H) + i];
    u[i] = s;
}

// ---------------------------------------------------------------------------
// scores[b,t] = dot(u[b], enc[b,t])   (one wave per (b,t) row)
__global__ __launch_bounds__(256) void k_scores(const float* __restrict__ u,
                                                const float* __restrict__ enc,
                                                float* __restrict__ sc) {
    int row = blockIdx.x * 4 + (threadIdx.x >> 6);   // 32768 rows
    int lane = threadIdx.x & 63;
    int b = row >> 9, t = row & 511;
    const float4* up = (const float4*)(u + (size_t)b * H);
    const float4* ep = (const float4*)(enc + ((size_t)b * T + t) * H);
    float s = 0.f;
#pragma unroll
    for (int it = 0; it < 4; ++it) {
        float4 uu = up[it * 64 + lane];
        float4 ee = ep[it * 64 + lane];
        s += uu.x * ee.x + uu.y * ee.y + uu.z * ee.z + uu.w * ee.w;
    }
#pragma unroll
    for (int o = 32; o; o >>= 1) s += __shfl_down(s, o, 64);
    if (lane == 0) sc[(size_t)b * T + t] = s;
}

// softmax over T=512 per b (one block per b, 512 threads)
__global__ void k_softmax(const float* __restrict__ sc, float* __restrict__ aw) {
    int b = blockIdx.x, t = threadIdx.x;
    float s = sc[(size_t)b * T + t];
    float m = s;
#pragma unroll
    for (int o = 32; o; o >>= 1) m = fmaxf(m, __shfl_down(m, o, 64));
    __shared__ float red[8], red2[8];
    int wid = t >> 6, lane = t & 63;
    if (lane == 0) red[wid] = m;
    __syncthreads();
    m = fmaxf(fmaxf(fmaxf(red[0], red[1]), fmaxf(red[2], red[3])),
              fmaxf(fmaxf(red[4], red[5]), fmaxf(red[6], red[7])));
    float e = expf(s - m);
    float sum = e;
#pragma unroll
    for (int o = 32; o; o >>= 1) sum += __shfl_down(sum, o, 64);
    if (lane == 0) red2[wid] = sum;
    __syncthreads();
    sum = red2[0] + red2[1] + red2[2] + red2[3] + red2[4] + red2[5] + red2[6] + red2[7];
    aw[(size_t)b * T + t] = e / sum;
}

// context partial: Pctx[tc][b][h] = sum_{t in chunk tc} aw[b,t]*enc[b,t,h]
__global__ __launch_bounds__(256) void k_ctx_part(const float* __restrict__ aw,
                                                  const float* __restrict__ enc,
                                                  float* __restrict__ Pctx) {
    int b = blockIdx.x >> 3, tc = blockIdx.x & 7;
    __shared__ float wsm[64];
    if (threadIdx.x < 64) wsm[threadIdx.x] = aw[(size_t)b * T + tc * 64 + threadIdx.x];
    __syncthreads();
    float4 acc = {0.f, 0.f, 0.f, 0.f};
    const float4* ebase = (const float4*)(enc + ((size_t)b * T + tc * 64) * H);
#pragma unroll 4
    for (int t = 0; t < 64; ++t) {
        float w = wsm[t];
        float4 e = ebase[t * 256 + threadIdx.x];
        acc.x += w * e.x; acc.y += w * e.y; acc.z += w * e.z; acc.w += w * e.w;
    }
    float4* pc = (float4*)(Pctx + ((size_t)(tc * 64 + b)) * H);
    pc[threadIdx.x] = acc;
}

// context sum -> cat[:, H:2H]
__global__ void k_ctxsum(const float* __restrict__ Pctx, float* __restrict__ cat) {
    int i = blockIdx.x * 256 + threadIdx.x;   // 65536
    int b = i >> 10, h = i & 1023;
    float c = 0.f;
#pragma unroll
    for (int tc = 0; tc < 8; ++tc) c += Pctx[((size_t)(tc * 64 + b)) * H + h];
    cat[(size_t)b * 2 * H + H + h] = c;
}

// co = tanh(sum partials + b_c)
__global__ void k_co(const float* __restrict__ Pc, const float* __restrict__ bc,
                     float* __restrict__ co) {
    int i = blockIdx.x * 256 + threadIdx.x;
    int h = i & 1023;
    float s = bc[h];
#pragma unroll
    for (int kt = 0; kt < 4; ++kt) s += Pc[kt * (B * H) + i];
    co[i] = tanhf(s);
}

// ---------------------------------------------------------------------------
// output GEMM: out[b,v] = sum_h co[b,h]*Wo[v,h] + bo[v]   (the big one: 206 MB)
__global__ __launch_bounds__(256) void k_out(const float* __restrict__ co,
                                             const float* __restrict__ Wo,
                                             const float* __restrict__ bo,
                                             float* __restrict__ out) {
    __shared__ __align__(16) float As[32][68];
    __shared__ __align__(16) float Bs[32][68];
    const int t = threadIdx.x;
    const int v0 = blockIdx.x * 64;
    const int tm = t >> 4, tn = t & 15;
    float acc[4][4] = {};
    for (int kk = 0; kk < H; kk += 32) {
#pragma unroll
        for (int i = 0; i < 8; ++i) {
            int idx = t + i * 256;
            int m = idx >> 5, k = idx & 31;
            As[k][m] = co[(size_t)m * H + kk + k];
            int v = v0 + m;
            Bs[k][m] = (v < V) ? Wo[(size_t)v * H + kk + k] : 0.f;
        }
        __syncthreads();
#pragma unroll
        for (int k = 0; k < 32; ++k) {
            float4 a = *(const float4*)&As[k][tm * 4];
            float4 b = *(const float4*)&Bs[k][tn * 4];
            float av[4] = {a.x, a.y, a.z, a.w};
            float bv[4] = {b.x, b.y, b.z, b.w};
#pragma unroll
            for (int i = 0; i < 4; ++i)
#pragma unroll
                for (int j = 0; j < 4; ++j) acc[i][j] += av[i] * bv[j];
        }
        __syncthreads();
    }
#pragma unroll
    for (int i = 0; i < 4; ++i) {
        int b_ = tm * 4 + i;
#pragma unroll
        for (int j = 0; j < 4; ++j) {
            int v = v0 + tn * 4 + j;
            if (v < V) out[(size_t)b_ * V + v] = acc[i][j] + bo[v];
        }
    }
}

// ---------------------------------------------------------------------------
extern "C" void kernel_launch(void* const* d_in, const int* in_sizes, int n_in,
                              void* d_out, int out_size, void* d_ws, size_t ws_size,
                              hipStream_t stream) {
    (void)in_sizes; (void)n_in; (void)out_size; (void)ws_size;
    const int*   seq = (const int*)d_in[0];
    const float* h0  = (const float*)d_in[1];
    const float* enc = (const float*)d_in[2];
    const float* emb = (const float*)d_in[3];
    const float* Wih = (const float*)d_in[4];
    const float* Whh = (const float*)d_in[5];
    const float* bih = (const float*)d_in[6];
    const float* bhh = (const float*)d_in[7];
    const float* Wa  = (const float*)d_in[8];
    // d_in[9] = b_a: softmax over t is invariant to the per-b constant h·b_a -> unused
    const float* Wc  = (const float*)d_in[10];
    const float* bc  = (const float*)d_in[11];
    const float* Wo  = (const float*)d_in[12];
    const float* bo  = (const float*)d_in[13];

    float* out = (float*)d_out;
    float* hid = out + (size_t)B * V;

    float* ws   = (float*)d_ws;
    float* X    = ws;               // 65536
    float* Pgi  = X + 65536;        // 4*64*3072 = 786432   (reused as Pctx later)
    float* Pgh  = Pgi + 786432;     // 786432               (reused as Pc later)
    float* cat  = Pgh + 786432;     // 64*2048 = 131072
    float* Pu   = cat + 131072;     // 4*64*1024 = 262144
    float* u    = Pu + 262144;      // 65536
    float* sc   = u + 65536;        // 32768
    float* aw   = sc + 32768;       // 32768
    float* co   = aw + 32768;       // 65536
    float* Pctx = Pgi;              // 8*64*1024 = 524288 fits in Pgi region
    float* Pc   = Pgh;              // 262144 fits in Pgh region

    k_embed<<<256, 256, 0, stream>>>(seq, emb, X);
    gemm64<true><<<dim3(48, 4), 256, 0, stream>>>(X, H, Wih, H, Pgi, 3 * H, 256);
    gemm64<true><<<dim3(48, 4), 256, 0, stream>>>(h0, H, Whh, H, Pgh, 3 * H, 256);
    k_gru<<<256, 256, 0, stream>>>(Pgi, Pgh, bih, bhh, h0, cat, hid);
    gemm64<false><<<dim3(16, 4), 256, 0, stream>>>(cat, 2 * H, Wa, H, Pu, H, 256);
    k_sumu<<<256, 256, 0, stream>>>(Pu, u);
    k_scores<<<8192, 256, 0, stream>>>(u, enc, sc);
    k_softmax<<<64, 512, 0, stream>>>(sc, aw);
    k_ctx_part<<<512, 256, 0, stream>>>(aw, enc, Pctx);
    k_ctxsum<<<256, 256, 0, stream>>>(Pctx, cat);
    gemm64<true><<<dim3(16, 4), 256, 0, stream>>>(cat, 2 * H, Wc, 2 * H, Pc, H, 512);
    k_co<<<256, 256, 0, stream>>>(Pc, bc, co);
    k_out<<<786, 256, 0, stream>>>(co, Wo, bo, out);
}

// Round 2
// 227.251 us; speedup vs baseline: 1.4832x; 1.4832x over previous
//
#include <hip/hip_runtime.h>
#include <cstdint>
#include <cstddef>

#define H 1024
#define V 50257
#define B 64
#define T 512

typedef __attribute__((ext_vector_type(8))) short bf16x8;
typedef __attribute__((ext_vector_type(4))) float f32x4;

__device__ __forceinline__ float sigmoidf_(float x) { return 1.0f / (1.0f + expf(-x)); }

__device__ __forceinline__ unsigned short f2bf(float x) {
    unsigned u = __float_as_uint(x);
    unsigned r = (u + 0x7FFFu + ((u >> 16) & 1u)) >> 16;
    return (unsigned short)r;
}

// ---------------------------------------------------------------------------
// Embedding gather: X[b][h] = emb[seq[b]][h]
__global__ void k_embed(const int* __restrict__ seq, const float* __restrict__ emb,
                        float* __restrict__ X) {
    int i = blockIdx.x * 256 + threadIdx.x;   // 65536 total
    int b = i >> 10, h = i & 1023;
    X[i] = emb[(size_t)seq[b] * H + h];
}

// ---------------------------------------------------------------------------
// Generic split-K tiled GEMM, M fixed = 64 (all batch rows), BN = 64, BK = 32.
template <bool BT>
__global__ __launch_bounds__(256) void gemm64(const float* __restrict__ A, int lda,
                                              const float* __restrict__ Bm, int ldb,
                                              float* __restrict__ Cp, int N, int KC) {
    __shared__ __align__(16) float As[32][68];
    __shared__ __align__(16) float Bs[32][68];
    const int t = threadIdx.x;
    const int n0 = blockIdx.x * 64;
    const int k0 = blockIdx.y * KC;
    const int tm = t >> 4, tn = t & 15;
    float acc[4][4] = {};
    for (int kk = k0; kk < k0 + KC; kk += 32) {
#pragma unroll
        for (int i = 0; i < 8; ++i) {
            int idx = t + i * 256;
            int m = idx >> 5, k = idx & 31;
            As[k][m] = A[(size_t)m * lda + kk + k];
        }
        if (BT) {
#pragma unroll
            for (int i = 0; i < 8; ++i) {
                int idx = t + i * 256;
                int n = idx >> 5, k = idx & 31;
                Bs[k][n] = Bm[(size_t)(n0 + n) * ldb + kk + k];
            }
        } else {
#pragma unroll
            for (int i = 0; i < 8; ++i) {
                int k = (t >> 6) + i * 4, n = t & 63;
                Bs[k][n] = Bm[(size_t)(kk + k) * ldb + n0 + n];
            }
        }
        __syncthreads();
#pragma unroll
        for (int k = 0; k < 32; ++k) {
            float4 a = *(const float4*)&As[k][tm * 4];
            float4 b = *(const float4*)&Bs[k][tn * 4];
            float av[4] = {a.x, a.y, a.z, a.w};
            float bv[4] = {b.x, b.y, b.z, b.w};
#pragma unroll
            for (int i = 0; i < 4; ++i)
#pragma unroll
                for (int j = 0; j < 4; ++j) acc[i][j] += av[i] * bv[j];
        }
        __syncthreads();
    }
    float* C = Cp + (size_t)blockIdx.y * 64 * N;
#pragma unroll
    for (int i = 0; i < 4; ++i)
#pragma unroll
        for (int j = 0; j < 4; ++j)
            C[(size_t)(tm * 4 + i) * N + n0 + tn * 4 + j] = acc[i][j];
}

// ---------------------------------------------------------------------------
__global__ void k_gru(const float* __restrict__ Pgi, const float* __restrict__ Pgh,
                      const float* __restrict__ bih, const float* __restrict__ bhh,
                      const float* __restrict__ h0, float* __restrict__ cat,
                      float* __restrict__ hid) {
    int i = blockIdx.x * 256 + threadIdx.x;   // 65536
    int b = i >> 10, h = i & 1023;
    float gr = bih[h], gz = bih[H + h], gn = bih[2 * H + h];
    float hr = bhh[h], hz = bhh[H + h], hn = bhh[2 * H + h];
#pragma unroll
    for (int kt = 0; kt < 4; ++kt) {
        const float* pi = Pgi + (size_t)kt * B * 3 * H + (size_t)b * 3 * H;
        const float* ph = Pgh + (size_t)kt * B * 3 * H + (size_t)b * 3 * H;
        gr += pi[h]; gz += pi[H + h]; gn += pi[2 * H + h];
        hr += ph[h]; hz += ph[H + h]; hn += ph[2 * H + h];
    }
    float r = sigmoidf_(gr + hr);
    float z = sigmoidf_(gz + hz);
    float n = tanhf(gn + r * hn);
    float hv = (1.0f - z) * n + z * h0[i];
    cat[(size_t)b * 2 * H + h] = hv;
    hid[i] = hv;
}

__global__ void k_sumu(const float* __restrict__ Pu, float* __restrict__ u) {
    int i = blockIdx.x * 256 + threadIdx.x;
    float s = 0.f;
#pragma unroll
    for (int kt = 0; kt < 4; ++kt) s += Pu[kt * (B * H) + i];
    u[i] = s;
}

// ---------------------------------------------------------------------------
__global__ __launch_bounds__(256) void k_scores(const float* __restrict__ u,
                                                const float* __restrict__ enc,
                                                float* __restrict__ sc) {
    int row = blockIdx.x * 4 + (threadIdx.x >> 6);   // 32768 rows
    int lane = threadIdx.x & 63;
    int b = row >> 9, t = row & 511;
    const float4* up = (const float4*)(u + (size_t)b * H);
    const float4* ep = (const float4*)(enc + ((size_t)b * T + t) * H);
    float s = 0.f;
#pragma unroll
    for (int it = 0; it < 4; ++it) {
        float4 uu = up[it * 64 + lane];
        float4 ee = ep[it * 64 + lane];
        s += uu.x * ee.x + uu.y * ee.y + uu.z * ee.z + uu.w * ee.w;
    }
#pragma unroll
    for (int o = 32; o; o >>= 1) s += __shfl_down(s, o, 64);
    if (lane == 0) sc[(size_t)b * T + t] = s;
}

__global__ void k_softmax(const float* __restrict__ sc, float* __restrict__ aw) {
    int b = blockIdx.x, t = threadIdx.x;
    float s = sc[(size_t)b * T + t];
    float m = s;
#pragma unroll
    for (int o = 32; o; o >>= 1) m = fmaxf(m, __shfl_down(m, o, 64));
    __shared__ float red[8], red2[8];
    int wid = t >> 6, lane = t & 63;
    if (lane == 0) red[wid] = m;
    __syncthreads();
    m = fmaxf(fmaxf(fmaxf(red[0], red[1]), fmaxf(red[2], red[3])),
              fmaxf(fmaxf(red[4], red[5]), fmaxf(red[6], red[7])));
    float e = expf(s - m);
    float sum = e;
#pragma unroll
    for (int o = 32; o; o >>= 1) sum += __shfl_down(sum, o, 64);
    if (lane == 0) red2[wid] = sum;
    __syncthreads();
    sum = red2[0] + red2[1] + red2[2] + red2[3] + red2[4] + red2[5] + red2[6] + red2[7];
    aw[(size_t)b * T + t] = e / sum;
}

__global__ __launch_bounds__(256) void k_ctx_part(const float* __restrict__ aw,
                                                  const float* __restrict__ enc,
                                                  float* __restrict__ Pctx) {
    int b = blockIdx.x >> 3, tc = blockIdx.x & 7;
    __shared__ float wsm[64];
    if (threadIdx.x < 64) wsm[threadIdx.x] = aw[(size_t)b * T + tc * 64 + threadIdx.x];
    __syncthreads();
    float4 acc = {0.f, 0.f, 0.f, 0.f};
    const float4* ebase = (const float4*)(enc + ((size_t)b * T + tc * 64) * H);
#pragma unroll 4
    for (int t = 0; t < 64; ++t) {
        float w = wsm[t];
        float4 e = ebase[t * 256 + threadIdx.x];
        acc.x += w * e.x; acc.y += w * e.y; acc.z += w * e.z; acc.w += w * e.w;
    }
    float4* pc = (float4*)(Pctx + ((size_t)(tc * 64 + b)) * H);
    pc[threadIdx.x] = acc;
}

__global__ void k_ctxsum(const float* __restrict__ Pctx, float* __restrict__ cat) {
    int i = blockIdx.x * 256 + threadIdx.x;   // 65536
    int b = i >> 10, h = i & 1023;
    float c = 0.f;
#pragma unroll
    for (int tc = 0; tc < 8; ++tc) c += Pctx[((size_t)(tc * 64 + b)) * H + h];
    cat[(size_t)b * 2 * H + H + h] = c;
}

__global__ void k_co(const float* __restrict__ Pc, const float* __restrict__ bc,
                     float* __restrict__ co) {
    int i = blockIdx.x * 256 + threadIdx.x;
    int h = i & 1023;
    float s = bc[h];
#pragma unroll
    for (int kt = 0; kt < 4; ++kt) s += Pc[kt * (B * H) + i];
    co[i] = tanhf(s);
}

// ---------------------------------------------------------------------------
// Output GEMM via bf16 MFMA with on-the-fly fp32->bf16 conversion.
// out[b,v] = sum_h co[b,h]*Wo[v,h] + bo[v].  M=64, N=V, K=H.
// Tile: BN=128 v-rows, BK=64, 256 threads (4 waves), double-buffered LDS.
// A (co) and B (Wo) are both row-major-in-K; A-frag and B-frag use the SAME
// lane->k mapping so any k-permutation error cancels (sum over k is
// permutation-invariant). C/D layout: col=lane&15, row=(lane>>4)*4+reg (m89).
// LDS XOR swizzle (ushort units): c_s = c ^ ((row&7)<<3)  [G4: 128B row stride]
__global__ __launch_bounds__(256) void k_out_mfma(const float* __restrict__ co,
                                                  const float* __restrict__ Wo,
                                                  const float* __restrict__ bo,
                                                  float* __restrict__ out) {
    __shared__ __align__(16) unsigned short As[2][64 * 64];    // 8 KB x2
    __shared__ __align__(16) unsigned short Bs[2][128 * 64];   // 16 KB x2

    const int t = threadIdx.x;
    const int lane = t & 63;
    const int w = t >> 6;          // wave 0..3 -> n-quad
    const int li = lane & 15;
    const int qu = lane >> 4;
    const int v0 = blockIdx.x * 128;
    const int tr = t >> 4;         // 0..15 (row within pass)
    const int tc = t & 15;         // float4 col

    f32x4 acc[4][2];
#pragma unroll
    for (int ms = 0; ms < 4; ++ms)
#pragma unroll
        for (int ns = 0; ns < 2; ++ns) acc[ms][ns] = (f32x4){0.f, 0.f, 0.f, 0.f};

    float4 wreg[8], creg[4];
    const float4 zero4 = {0.f, 0.f, 0.f, 0.f};

#define LOAD_TILES(KK)                                                          \
    {                                                                           \
        _Pragma("unroll")                                                       \
        for (int p = 0; p < 8; ++p) {                                           \
            int r = tr + p * 16;                                                \
            int v = v0 + r;                                                     \
            wreg[p] = (v < V) ? *(const float4*)&Wo[(size_t)v * H + (KK) + tc * 4] \
                              : zero4;                                          \
        }                                                                       \
        _Pragma("unroll")                                                       \
        for (int p = 0; p < 4; ++p) {                                           \
            int r = tr + p * 16;                                                \
            creg[p] = *(const float4*)&co[(size_t)r * H + (KK) + tc * 4];       \
        }                                                                       \
    }

#define CVT_WRITE(BUF)                                                          \
    {                                                                           \
        _Pragma("unroll")                                                       \
        for (int p = 0; p < 8; ++p) {                                           \
            int r = tr + p * 16;                                                \
            int cs = (tc * 4) ^ ((r & 7) << 3);                                 \
            ushort4 pk;                                                         \
            pk.x = f2bf(wreg[p].x); pk.y = f2bf(wreg[p].y);                     \
            pk.z = f2bf(wreg[p].z); pk.w = f2bf(wreg[p].w);                     \
            *(ushort4*)&Bs[BUF][r * 64 + cs] = pk;                              \
        }                                                                       \
        _Pragma("unroll")                                                       \
        for (int p = 0; p < 4; ++p) {                                           \
            int r = tr + p * 16;                                                \
            int cs = (tc * 4) ^ ((r & 7) << 3);                                 \
            ushort4 pk;                                                         \
            pk.x = f2bf(creg[p].x); pk.y = f2bf(creg[p].y);                     \
            pk.z = f2bf(creg[p].z); pk.w = f2bf(creg[p].w);                     \
            *(ushort4*)&As[BUF][r * 64 + cs] = pk;                              \
        }                                                                       \
    }

    LOAD_TILES(0);
    CVT_WRITE(0);
    __syncthreads();

    for (int it = 0; it < 16; ++it) {
        if (it < 15) LOAD_TILES((it + 1) * 64);

        const int buf = it & 1;
#pragma unroll
        for (int ks = 0; ks < 2; ++ks) {
            bf16x8 af[4];
#pragma unroll
            for (int ms = 0; ms < 4; ++ms) {
                int row = ms * 16 + li;
                int cs = (ks * 32 + qu * 8) ^ ((row & 7) << 3);
                af[ms] = *(const bf16x8*)&As[buf][row * 64 + cs];
            }
#pragma unroll
            for (int ns = 0; ns < 2; ++ns) {
                int brow = w * 32 + ns * 16 + li;
                int cs = (ks * 32 + qu * 8) ^ ((brow & 7) << 3);
                bf16x8 bfr = *(const bf16x8*)&Bs[buf][brow * 64 + cs];
#pragma unroll
                for (int ms = 0; ms < 4; ++ms)
                    acc[ms][ns] = __builtin_amdgcn_mfma_f32_16x16x32_bf16(
                        af[ms], bfr, acc[ms][ns], 0, 0, 0);
            }
        }

        if (it < 15) CVT_WRITE(buf ^ 1);
        __syncthreads();
    }

#pragma unroll
    for (int ns = 0; ns < 2; ++ns) {
        int v = v0 + w * 32 + ns * 16 + li;
        if (v < V) {
            float bov = bo[v];
#pragma unroll
            for (int ms = 0; ms < 4; ++ms) {
#pragma unroll
                for (int j = 0; j < 4; ++j) {
                    int b_ = ms * 16 + qu * 4 + j;
                    out[(size_t)b_ * V + v] = acc[ms][ns][j] + bov;
                }
            }
        }
    }
#undef LOAD_TILES
#undef CVT_WRITE
}

// ---------------------------------------------------------------------------
extern "C" void kernel_launch(void* const* d_in, const int* in_sizes, int n_in,
                              void* d_out, int out_size, void* d_ws, size_t ws_size,
                              hipStream_t stream) {
    (void)in_sizes; (void)n_in; (void)out_size; (void)ws_size;
    const int*   seq = (const int*)d_in[0];
    const float* h0  = (const float*)d_in[1];
    const float* enc = (const float*)d_in[2];
    const float* emb = (const float*)d_in[3];
    const float* Wih = (const float*)d_in[4];
    const float* Whh = (const float*)d_in[5];
    const float* bih = (const float*)d_in[6];
    const float* bhh = (const float*)d_in[7];
    const float* Wa  = (const float*)d_in[8];
    // d_in[9] = b_a: softmax over t is invariant to the per-b constant h·b_a -> unused
    const float* Wc  = (const float*)d_in[10];
    const float* bc  = (const float*)d_in[11];
    const float* Wo  = (const float*)d_in[12];
    const float* bo  = (const float*)d_in[13];

    float* out = (float*)d_out;
    float* hid = out + (size_t)B * V;

    float* ws   = (float*)d_ws;
    float* X    = ws;               // 65536
    float* Pgi  = X + 65536;        // 786432  (reused as Pctx later)
    float* Pgh  = Pgi + 786432;     // 786432  (reused as Pc later)
    float* cat  = Pgh + 786432;     // 131072
    float* Pu   = cat + 131072;     // 262144
    float* u    = Pu + 262144;      // 65536
    float* sc   = u + 65536;        // 32768
    float* aw   = sc + 32768;       // 32768
    float* co   = aw + 32768;       // 65536
    float* Pctx = Pgi;              // 524288 fits
    float* Pc   = Pgh;              // 262144 fits

    k_embed<<<256, 256, 0, stream>>>(seq, emb, X);
    gemm64<true><<<dim3(48, 4), 256, 0, stream>>>(X, H, Wih, H, Pgi, 3 * H, 256);
    gemm64<true><<<dim3(48, 4), 256, 0, stream>>>(h0, H, Whh, H, Pgh, 3 * H, 256);
    k_gru<<<256, 256, 0, stream>>>(Pgi, Pgh, bih, bhh, h0, cat, hid);
    gemm64<false><<<dim3(16, 4), 256, 0, stream>>>(cat, 2 * H, Wa, H, Pu, H, 256);
    k_sumu<<<256, 256, 0, stream>>>(Pu, u);
    k_scores<<<8192, 256, 0, stream>>>(u, enc, sc);
    k_softmax<<<64, 512, 0, stream>>>(sc, aw);
    k_ctx_part<<<512, 256, 0, stream>>>(aw, enc, Pctx);
    k_ctxsum<<<256, 256, 0, stream>>>(Pctx, cat);
    gemm64<true><<<dim3(16, 4), 256, 0, stream>>>(cat, 2 * H, Wc, 2 * H, Pc, H, 512);
    k_co<<<256, 256, 0, stream>>>(Pc, bc, co);
    k_out_mfma<<<(V + 127) / 128, 256, 0, stream>>>(co, Wo, bo, out);
}